// Round 2
// baseline (8893.151 us; speedup 1.0000x reference)
//
#include <hip/hip_runtime.h>
#include <math.h>

#define BATCH  4
#define SEQ    1024
#define DM     512      // d_model
#define DI     2048     // d_inner
#define NH     8
#define DH     64
#define NL     6
#define NOUT   2

static constexpr float SQRT_D = 22.627416997969522f;  // sqrt(512)

// ---------------------------------------------------------------------------
// Embedding: h[b,s,d] = emb[x[b,s]][d]*sqrt(D) + pos[s,d]
// ---------------------------------------------------------------------------
__global__ __launch_bounds__(256) void k_embed(const int* __restrict__ x,
                                               const float* __restrict__ emb,
                                               const float* __restrict__ pos,
                                               float* __restrict__ h) {
    const int idx = blockIdx.x * 256 + threadIdx.x;   // float4 index
    const int d4  = idx & 127;                        // DM/4 = 128
    const int bs  = idx >> 7;                         // [0, 4096)
    const int s   = bs & (SEQ - 1);
    const int tok = x[bs];
    const float4 e = ((const float4*)emb)[tok * 128 + d4];
    const float4 p = ((const float4*)pos)[s * 128 + d4];
    float4 r;
    r.x = e.x * SQRT_D + p.x;
    r.y = e.y * SQRT_D + p.y;
    r.z = e.z * SQRT_D + p.z;
    r.w = e.w * SQRT_D + p.w;
    ((float4*)h)[idx] = r;
}

// ---------------------------------------------------------------------------
// f32 tiled GEMM: C[M,N] = A[M,K] @ B[K,N] + bias[N]  (optional relu)
// 64x64 tile, BK=16, 256 threads, 4x4 per thread. M,N div 64; K div 16.
// ---------------------------------------------------------------------------
template <int RELU>
__global__ __launch_bounds__(256) void k_gemm(const float* __restrict__ A,
                                              const float* __restrict__ B,
                                              const float* __restrict__ bias,
                                              float* __restrict__ C,
                                              int M, int N, int K) {
    __shared__ float As[16][68];   // As[k][m]; pad 68 -> conflict-free stores, aligned f4 reads
    __shared__ float Bs[16][64];   // Bs[k][n]

    const int n0 = blockIdx.x << 6;
    const int m0 = blockIdx.y << 6;
    const int t  = threadIdx.x;
    const int tx = t & 15, ty = t >> 4;

    const int ak = t & 15;   // k within tile for A loads
    const int ar = t >> 4;   // row base for A loads
    const int bk = t >> 6;   // k row base for B loads
    const int bc = t & 63;   // col for B loads

    float acc[4][4] = {};

    for (int k0 = 0; k0 < K; k0 += 16) {
#pragma unroll
        for (int p = 0; p < 4; ++p)
            As[ak][ar + (p << 4)] = A[(size_t)(m0 + ar + (p << 4)) * K + k0 + ak];
#pragma unroll
        for (int p = 0; p < 4; ++p)
            Bs[bk + (p << 2)][bc] = B[(size_t)(k0 + bk + (p << 2)) * N + n0 + bc];
        __syncthreads();

#pragma unroll
        for (int kk = 0; kk < 16; ++kk) {
            const float4 av = *(const float4*)&As[kk][ty << 2];
            const float4 bv = *(const float4*)&Bs[kk][tx << 2];
            const float aq[4] = {av.x, av.y, av.z, av.w};
            const float bq[4] = {bv.x, bv.y, bv.z, bv.w};
#pragma unroll
            for (int i = 0; i < 4; ++i)
#pragma unroll
                for (int j = 0; j < 4; ++j) acc[i][j] += aq[i] * bq[j];
        }
        __syncthreads();
    }

    const float4 b4 = *(const float4*)&bias[n0 + (tx << 2)];
#pragma unroll
    for (int i = 0; i < 4; ++i) {
        float4 r;
        r.x = acc[i][0] + b4.x;
        r.y = acc[i][1] + b4.y;
        r.z = acc[i][2] + b4.z;
        r.w = acc[i][3] + b4.w;
        if (RELU) {
            r.x = fmaxf(r.x, 0.f); r.y = fmaxf(r.y, 0.f);
            r.z = fmaxf(r.z, 0.f); r.w = fmaxf(r.w, 0.f);
        }
        *(float4*)&C[(size_t)(m0 + (ty << 2) + i) * N + n0 + (tx << 2)] = r;
    }
}

// ---------------------------------------------------------------------------
// Flash-style relative attention.
// Q,K,V: [B,S,DM] with head hd at cols hd*64..; E: [SEQ,DH] for this layer.
// Srel[i][c] = (c<=i) ? dot(q_i, E[1023-i+c]) : 0 ; logits=(QK^T+Srel)/8
// grid (16,8,4) = (qtile, head, batch); 256 threads.
// Thread t owns (row = t&63, output cols (t>>6)*16 .. +15).
// ---------------------------------------------------------------------------
__global__ __launch_bounds__(256) void k_attn(const float* __restrict__ Q,
                                              const float* __restrict__ K,
                                              const float* __restrict__ V,
                                              const float* __restrict__ E,
                                              float* __restrict__ O) {
    __shared__ float Qs[64][65];
    __shared__ float KVs[64][65];   // K tile, then V tile (sequenced)
    __shared__ float Ss[64][65];
    __shared__ float m_s[64], l_s[64], a_s[64];

    const int i0 = blockIdx.x << 6;
    const int hd = blockIdx.y;
    const int b  = blockIdx.z;
    const int t   = threadIdx.x;
    const int row = t & 63;
    const int cg  = t >> 6;  // 0..3

    const size_t base = (size_t)b * SEQ * DM + hd * DH;

    // load Q tile (64x64)
#pragma unroll
    for (int p = 0; p < 4; ++p) {
        int li = t + (p << 8);
        int r = li >> 4, q4 = li & 15;
        const float4 v = *(const float4*)(Q + base + (size_t)(i0 + r) * DM + (q4 << 2));
        float* dst = &Qs[r][q4 << 2];
        dst[0] = v.x; dst[1] = v.y; dst[2] = v.z; dst[3] = v.w;
    }
    if (t < 64) { m_s[t] = -1e30f; l_s[t] = 0.f; }

    float o[16];
#pragma unroll
    for (int j = 0; j < 16; ++j) o[j] = 0.f;

    const int i = i0 + row;

    for (int c0 = 0; c0 < SEQ; c0 += 64) {
        // load K tile
#pragma unroll
        for (int p = 0; p < 4; ++p) {
            int li = t + (p << 8);
            int r = li >> 4, q4 = li & 15;
            const float4 v = *(const float4*)(K + base + (size_t)(c0 + r) * DM + (q4 << 2));
            float* dst = &KVs[r][q4 << 2];
            dst[0] = v.x; dst[1] = v.y; dst[2] = v.z; dst[3] = v.w;
        }
        __syncthreads();   // Qs (first iter) + K tile visible

        // S = Q K^T for this thread's 16 columns
        float sv[16];
#pragma unroll
        for (int j = 0; j < 16; ++j) sv[j] = 0.f;
        for (int d = 0; d < 64; ++d) {
            const float qv = Qs[row][d];
#pragma unroll
            for (int j = 0; j < 16; ++j) sv[j] += qv * KVs[(cg << 4) + j][d];
        }

        // + Srel (only where key index c <= query index i)
        const int cbase = c0 + (cg << 4);
        int nact = i - cbase + 1;
        if (nact > 0) {
            if (nact > 16) nact = 16;
            const float4* Eb = (const float4*)(E + ((size_t)(1023 - i + cbase) << 6));
            for (int d4 = 0; d4 < 16; ++d4) {
                const int d = d4 << 2;
                const float q0 = Qs[row][d + 0], q1 = Qs[row][d + 1];
                const float q2 = Qs[row][d + 2], q3 = Qs[row][d + 3];
                for (int j = 0; j < nact; ++j) {
                    const float4 ev = Eb[(j << 4) + d4];  // E row (1023-i+cbase+j)
                    sv[j] += q0 * ev.x + q1 * ev.y + q2 * ev.z + q3 * ev.w;
                }
            }
        }
#pragma unroll
        for (int j = 0; j < 16; ++j) Ss[row][(cg << 4) + j] = sv[j] * 0.125f;
        __syncthreads();   // S tile complete; K tile consumed

        // load V tile into same LDS; wave0 does online softmax concurrently
#pragma unroll
        for (int p = 0; p < 4; ++p) {
            int li = t + (p << 8);
            int r = li >> 4, q4 = li & 15;
            const float4 v = *(const float4*)(V + base + (size_t)(c0 + r) * DM + (q4 << 2));
            float* dst = &KVs[r][q4 << 2];
            dst[0] = v.x; dst[1] = v.y; dst[2] = v.z; dst[3] = v.w;
        }
        if (t < 64) {
            const float mo = m_s[t];
            float mt = -1e30f;
            for (int c = 0; c < 64; ++c) mt = fmaxf(mt, Ss[t][c]);
            const float mn = fmaxf(mo, mt);
            const float al = __expf(mo - mn);
            float ssum = 0.f;
            for (int c = 0; c < 64; ++c) {
                const float pv = __expf(Ss[t][c] - mn);
                Ss[t][c] = pv;        // P written back in place
                ssum += pv;
            }
            m_s[t] = mn;
            l_s[t] = l_s[t] * al + ssum;
            a_s[t] = al;
        }
        __syncthreads();   // P + V tile + alpha visible

        const float al = a_s[row];
#pragma unroll
        for (int j = 0; j < 16; ++j) o[j] *= al;
        for (int c = 0; c < 64; ++c) {
            const float pv = Ss[row][c];
#pragma unroll
            for (int j = 0; j < 16; ++j) o[j] += pv * KVs[c][(cg << 4) + j];
        }
        __syncthreads();   // protect Ss/KVs before next iteration
    }

    const float inv = 1.f / l_s[row];
    const size_t ob = base + (size_t)i * DM + (cg << 4);
#pragma unroll
    for (int j4 = 0; j4 < 4; ++j4) {
        float4 r;
        r.x = o[j4 * 4 + 0] * inv;
        r.y = o[j4 * 4 + 1] * inv;
        r.z = o[j4 * 4 + 2] * inv;
        r.w = o[j4 * 4 + 3] * inv;
        *(float4*)(O + ob + (j4 << 2)) = r;
    }
}

// ---------------------------------------------------------------------------
// Y[r,:] = LayerNorm(A[r,:] + R[r,:]) * sc + bi     (one block per row, 128 thr)
// Safe when Y aliases A (each thread reads only the float4 it writes).
// ---------------------------------------------------------------------------
__global__ __launch_bounds__(128) void k_ln(const float* __restrict__ A,
                                            const float* __restrict__ R,
                                            const float* __restrict__ sc,
                                            const float* __restrict__ bi,
                                            float* __restrict__ Y) {
    const int r = blockIdx.x, t = threadIdx.x;
    const float4 a = ((const float4*)(A + (size_t)r * DM))[t];
    const float4 b = ((const float4*)(R + (size_t)r * DM))[t];
    float4 v;
    v.x = a.x + b.x; v.y = a.y + b.y; v.z = a.z + b.z; v.w = a.w + b.w;

    float s = v.x + v.y + v.z + v.w;
#pragma unroll
    for (int o = 32; o > 0; o >>= 1) s += __shfl_down(s, o, 64);
    __shared__ float r1[2], r2[2];
    if ((t & 63) == 0) r1[t >> 6] = s;
    __syncthreads();
    const float mean = (r1[0] + r1[1]) * (1.f / 512.f);

    float4 d;
    d.x = v.x - mean; d.y = v.y - mean; d.z = v.z - mean; d.w = v.w - mean;
    float q = d.x * d.x + d.y * d.y + d.z * d.z + d.w * d.w;
#pragma unroll
    for (int o = 32; o > 0; o >>= 1) q += __shfl_down(q, o, 64);
    if ((t & 63) == 0) r2[t >> 6] = q;
    __syncthreads();
    const float rs = rsqrtf((r2[0] + r2[1]) * (1.f / 512.f) + 1e-6f);

    const float4 s4 = ((const float4*)sc)[t];
    const float4 b4 = ((const float4*)bi)[t];
    float4 y;
    y.x = d.x * rs * s4.x + b4.x;
    y.y = d.y * rs * s4.y + b4.y;
    y.z = d.z * rs * s4.z + b4.z;
    y.w = d.w * rs * s4.w + b4.w;
    ((float4*)(Y + (size_t)r * DM))[t] = y;
}

// ---------------------------------------------------------------------------
// out[b,o] = tanh(h[b,0,:] @ Wf[:,o] + bf[o]).  1 block, 8 waves, wave per (b,o).
// ---------------------------------------------------------------------------
__global__ __launch_bounds__(512) void k_head(const float* __restrict__ h,
                                              const float* __restrict__ Wf,
                                              const float* __restrict__ bf,
                                              float* __restrict__ out) {
    const int t = threadIdx.x;
    const int w = t >> 6, lane = t & 63;
    const int b = w >> 1, oo = w & 1;
    float s = 0.f;
    for (int d = lane; d < DM; d += 64)
        s += h[(size_t)b * SEQ * DM + d] * Wf[d * NOUT + oo];
#pragma unroll
    for (int o = 32; o > 0; o >>= 1) s += __shfl_down(s, o, 64);
    if (lane == 0) out[b * NOUT + oo] = tanhf(s + bf[oo]);
}

// ---------------------------------------------------------------------------
extern "C" void kernel_launch(void* const* d_in, const int* in_sizes, int n_in,
                              void* d_out, int out_size, void* d_ws, size_t ws_size,
                              hipStream_t stream) {
    const int*   x    = (const int*)d_in[0];
    const float* emb  = (const float*)d_in[1];
    const float* pos  = (const float*)d_in[2];
    const float* Wq   = (const float*)d_in[3];
    const float* bq   = (const float*)d_in[4];
    const float* Wk   = (const float*)d_in[5];
    const float* bk   = (const float*)d_in[6];
    const float* Wv   = (const float*)d_in[7];
    const float* bv   = (const float*)d_in[8];
    const float* Wo   = (const float*)d_in[9];
    const float* bo   = (const float*)d_in[10];
    const float* E    = (const float*)d_in[11];
    const float* W1   = (const float*)d_in[12];
    const float* b1   = (const float*)d_in[13];
    const float* W2   = (const float*)d_in[14];
    const float* b2   = (const float*)d_in[15];
    const float* ln1s = (const float*)d_in[16];
    const float* ln1b = (const float*)d_in[17];
    const float* ln2s = (const float*)d_in[18];
    const float* ln2b = (const float*)d_in[19];
    const float* Wf   = (const float*)d_in[20];
    const float* bfp  = (const float*)d_in[21];
    float* out = (float*)d_out;
    float* ws  = (float*)d_ws;

    const size_t NT = (size_t)BATCH * SEQ * DM;   // 2,097,152 floats
    // Workspace map (total 6*NT floats = 48 MB):
    //   h  : [0,NT)     residual stream
    //   h1 : [NT,2NT)   post-LN1
    //   ab : [2NT,3NT)  q, then attn@Wo
    //   kb : [3NT,4NT)  k
    //   vb : [4NT,5NT)  v
    //   tb : [5NT,6NT)  attention concat output
    //   mid: [2NT,6NT)  FFN inner (aliases ab/kb/vb/tb, all dead by then)
    //   FFN output reuses h (dead after LN1); LN2 writes h in place (safe).
    float* h   = ws;
    float* h1  = ws + NT;
    float* ab  = ws + 2 * NT;
    float* kb  = ws + 3 * NT;
    float* vb  = ws + 4 * NT;
    float* tb  = ws + 5 * NT;
    float* mid = ws + 2 * NT;

    const int M = BATCH * SEQ;                 // 4096
    const dim3 gProj(DM / 64, M / 64);         // (8,64)
    const dim3 gFfn1(DI / 64, M / 64);         // (32,64)
    const dim3 gAttn(SEQ / 64, NH, BATCH);     // (16,8,4)

    k_embed<<<(BATCH * SEQ * DM / 4) / 256, 256, 0, stream>>>(x, emb, pos, h);

    for (int l = 0; l < NL; ++l) {
        const size_t wl = (size_t)l * DM * DM;
        k_gemm<0><<<gProj, 256, 0, stream>>>(h, Wq + wl, bq + l * DM, ab, M, DM, DM);
        k_gemm<0><<<gProj, 256, 0, stream>>>(h, Wk + wl, bk + l * DM, kb, M, DM, DM);
        k_gemm<0><<<gProj, 256, 0, stream>>>(h, Wv + wl, bv + l * DM, vb, M, DM, DM);
        k_attn<<<gAttn, 256, 0, stream>>>(ab, kb, vb, E + (size_t)l * SEQ * DH, tb);
        k_gemm<0><<<gProj, 256, 0, stream>>>(tb, Wo + wl, bo + l * DM, ab, M, DM, DM);
        k_ln<<<M, 128, 0, stream>>>(ab, h, ln1s + l * DM, ln1b + l * DM, h1);
        k_gemm<1><<<gFfn1, 256, 0, stream>>>(h1, W1 + (size_t)l * DM * DI, b1 + l * DI, mid, M, DI, DM);
        k_gemm<0><<<gProj, 256, 0, stream>>>(mid, W2 + (size_t)l * DI * DM, b2 + l * DM, h, M, DM, DI);
        k_ln<<<M, 128, 0, stream>>>(h, h1, ln2s + l * DM, ln2b + l * DM, h);
    }

    k_head<<<1, 512, 0, stream>>>(h, Wf, bfp, out);
}

// Round 4
// 1248.425 us; speedup vs baseline: 7.1235x; 7.1235x over previous
//
#include <hip/hip_runtime.h>
#include <math.h>

#define BATCH  4
#define SEQ    1024
#define DM     512
#define DI     2048
#define NH     8
#define DH     64
#define NL     6
#define NOUT   2

typedef unsigned short u16;
typedef short s16x8 __attribute__((ext_vector_type(8)));
typedef float f32x4 __attribute__((ext_vector_type(4)));
typedef unsigned short u16x4 __attribute__((ext_vector_type(4)));

#define MFMA16(a, b, c) __builtin_amdgcn_mfma_f32_16x16x32_bf16((a), (b), (c), 0, 0, 0)

static constexpr float SQRT_D = 22.627416997969522f;

__device__ __forceinline__ u16 f2b(float x) {           // f32 -> bf16 (RNE)
    union { float f; unsigned u; } v; v.f = x;
    unsigned r = v.u + 0x7fffu + ((v.u >> 16) & 1u);
    return (u16)(r >> 16);
}
__device__ __forceinline__ float b2f(u16 b) {
    union { unsigned u; float f; } v; v.u = ((unsigned)b) << 16; return v.f;
}

// ---------------------------------------------------------------------------
// Embedding: h = emb[x]*sqrt(D) + pos   (writes f32 h and bf16 hb)
// ---------------------------------------------------------------------------
__global__ __launch_bounds__(256) void k_embed(const int* __restrict__ x,
                                               const float* __restrict__ emb,
                                               const float* __restrict__ pos,
                                               float* __restrict__ h,
                                               u16* __restrict__ hb) {
    const int idx = blockIdx.x * 256 + threadIdx.x;   // float4 index
    const int d4  = idx & 127;
    const int bs  = idx >> 7;
    const int s   = bs & (SEQ - 1);
    const int tok = x[bs];
    const float4 e = ((const float4*)emb)[tok * 128 + d4];
    const float4 p = ((const float4*)pos)[s * 128 + d4];
    float4 r;
    r.x = e.x * SQRT_D + p.x;  r.y = e.y * SQRT_D + p.y;
    r.z = e.z * SQRT_D + p.z;  r.w = e.w * SQRT_D + p.w;
    ((float4*)h)[idx] = r;
    u16x4 rb = { f2b(r.x), f2b(r.y), f2b(r.z), f2b(r.w) };
    ((u16x4*)hb)[idx] = rb;
}

// ---------------------------------------------------------------------------
// Per-layer weight convert + transpose to bf16.
// Blocks 0..3071: 32x32 transpose tiles; blocks 3072..3135: E flat convert.
// dst layouts: Wqkvt [1536][512], Wot [512][512], W1t [2048][512], W2t [512][2048]
// ---------------------------------------------------------------------------
__global__ __launch_bounds__(256) void k_conv(const float* __restrict__ Wq, const float* __restrict__ Wk,
                                              const float* __restrict__ Wv, const float* __restrict__ Wo,
                                              const float* __restrict__ W1, const float* __restrict__ W2,
                                              const float* __restrict__ E,
                                              u16* __restrict__ Wqkvt, u16* __restrict__ Wot,
                                              u16* __restrict__ W1t,  u16* __restrict__ W2t,
                                              u16* __restrict__ Ebf, int layer) {
    const int tb = blockIdx.x;
    if (tb >= 3072) {                                   // E convert (no transpose)
        const int rem = tb - 3072;                      // 0..63
        const int idx = rem * 1024 + threadIdx.x * 4;   // elements
        const float4 v = *(const float4*)(E + (size_t)layer * SEQ * DH + idx);
        u16x4 o = { f2b(v.x), f2b(v.y), f2b(v.z), f2b(v.w) };
        *(u16x4*)(Ebf + idx) = o;
        return;
    }
    __shared__ float T[32][33];
    const float* src; u16* dst; int Ksz, Nsz, tk, tn;
    if (tb < 768) {
        const int mat = tb >> 8, rem = tb & 255;
        src = (mat == 0 ? Wq : (mat == 1 ? Wk : Wv)) + (size_t)layer * DM * DM;
        dst = Wqkvt + (size_t)mat * DM * DM;
        Ksz = 512; Nsz = 512; tk = rem & 15; tn = rem >> 4;
    } else if (tb < 1024) {
        const int rem = tb - 768;
        src = Wo + (size_t)layer * DM * DM; dst = Wot;
        Ksz = 512; Nsz = 512; tk = rem & 15; tn = rem >> 4;
    } else if (tb < 2048) {
        const int rem = tb - 1024;
        src = W1 + (size_t)layer * DM * DI; dst = W1t;
        Ksz = 512; Nsz = 2048; tk = rem & 15; tn = rem >> 4;   // tn 0..63
    } else {
        const int rem = tb - 2048;
        src = W2 + (size_t)layer * DI * DM; dst = W2t;
        Ksz = 2048; Nsz = 512; tk = rem >> 4; tn = rem & 15;   // tk 0..63
    }
    {
        const int rr = threadIdx.x >> 3, c4 = (threadIdx.x & 7) << 2;
        const float4 v = *(const float4*)(src + (size_t)(tk * 32 + rr) * Nsz + tn * 32 + c4);
        T[rr][c4 + 0] = v.x; T[rr][c4 + 1] = v.y; T[rr][c4 + 2] = v.z; T[rr][c4 + 3] = v.w;
    }
    __syncthreads();
    {
        const int nl = threadIdx.x >> 3, k4 = (threadIdx.x & 7) << 2;
        u16x4 o = { f2b(T[k4 + 0][nl]), f2b(T[k4 + 1][nl]), f2b(T[k4 + 2][nl]), f2b(T[k4 + 3][nl]) };
        *(u16x4*)(dst + (size_t)(tn * 32 + nl) * Ksz + tk * 32 + k4) = o;
    }
}

// ---------------------------------------------------------------------------
// MFMA GEMM: C[4096][N] = A[4096][K](bf16) @ Bt[N][K](bf16)^T + bias.
// 128x128 tile, BK=32, 256 thr = 4 waves (2x2 of 64x64). 16x16x32 bf16 MFMA.
// Segmented output (QKV): sel = n_glob>>seg_shift picks C segment + bias ptr.
// ---------------------------------------------------------------------------
template <int RELU, int WRITE_BF16>
__global__ __launch_bounds__(256) void k_mm(const u16* __restrict__ A,
                                            const u16* __restrict__ Bt,
                                            const float* __restrict__ bias0,
                                            const float* __restrict__ bias1,
                                            const float* __restrict__ bias2,
                                            float* __restrict__ Cf,
                                            u16* __restrict__ Cb,
                                            int K, int ldc, int seg_shift, size_t seg_stride) {
    __shared__ u16 As[128 * 40];    // stride 40 bf16 (80B): 2-way-max frag reads
    __shared__ u16 Bs[128 * 40];

    const int n0 = blockIdx.x << 7;
    const int m0 = blockIdx.y << 7;
    const int t  = threadIdx.x;
    const int lane = t & 63, w = t >> 6;
    const int n16 = lane & 15, quad = lane >> 4;
    const int wr = (w & 1) << 6;       // wave row offset 0/64
    const int wc = (w >> 1) << 6;      // wave col offset 0/64

    const f32x4 z = {0.f, 0.f, 0.f, 0.f};
    f32x4 acc[4][4];
#pragma unroll
    for (int i = 0; i < 4; ++i)
#pragma unroll
        for (int j = 0; j < 4; ++j) acc[i][j] = z;

    const int sr = t >> 2, sk = (t & 3) << 3;     // staging: row, k-chunk
    const u16* Ag = A  + (size_t)(m0 + sr) * K + sk;
    const u16* Bg = Bt + (size_t)(n0 + sr) * K + sk;

    for (int k0 = 0; k0 < K; k0 += 32) {
        __syncthreads();
        *(uint4*)&As[sr * 40 + sk]        = *(const uint4*)(Ag + k0);
        *(uint4*)&As[(sr + 64) * 40 + sk] = *(const uint4*)(Ag + (size_t)64 * K + k0);
        *(uint4*)&Bs[sr * 40 + sk]        = *(const uint4*)(Bg + k0);
        *(uint4*)&Bs[(sr + 64) * 40 + sk] = *(const uint4*)(Bg + (size_t)64 * K + k0);
        __syncthreads();

        s16x8 af[4], bfr[4];
#pragma unroll
        for (int rb = 0; rb < 4; ++rb)
            af[rb] = *(const s16x8*)&As[(wr + rb * 16 + n16) * 40 + quad * 8];
#pragma unroll
        for (int cb = 0; cb < 4; ++cb)
            bfr[cb] = *(const s16x8*)&Bs[(wc + cb * 16 + n16) * 40 + quad * 8];
#pragma unroll
        for (int rb = 0; rb < 4; ++rb)
#pragma unroll
            for (int cb = 0; cb < 4; ++cb)
                acc[rb][cb] = MFMA16(af[rb], bfr[cb], acc[rb][cb]);
    }

    const int sel = n0 >> seg_shift;
    const int colbase = (n0 & ((1 << seg_shift) - 1)) + wc;
    const float* bias = (sel == 0) ? bias0 : (sel == 1 ? bias1 : bias2);
    const size_t cbase = (size_t)sel * seg_stride;

#pragma unroll
    for (int cb = 0; cb < 4; ++cb) {
        const int col = colbase + cb * 16 + n16;
        const float bv = bias[col];
#pragma unroll
        for (int rb = 0; rb < 4; ++rb) {
#pragma unroll
            for (int rr = 0; rr < 4; ++rr) {
                const int row = m0 + wr + rb * 16 + quad * 4 + rr;
                float v = acc[rb][cb][rr] + bv;
                if (RELU) v = fmaxf(v, 0.f);
                const size_t idx = cbase + (size_t)row * ldc + col;
                if (WRITE_BF16) Cb[idx] = f2b(v);
                else            Cf[idx] = v;
            }
        }
    }
}

// ---------------------------------------------------------------------------
// MFMA flash relative attention (bf16 in/out, f32 softmax).
// grid (16, 8, 4) = (qtile, head, batch); 256 thr = 4 waves; wave w owns
// q-rows rw=w*16. Srel via QE = Q @ E_window^T (skew: Srel[ir][ic] =
// QE[ir][63+ic-ir], kept iff ic-ir <= i0-c0). logits=(QK^T+Srel)/8.
// ---------------------------------------------------------------------------
__global__ __launch_bounds__(256) void k_attn(const u16* __restrict__ Qg,
                                              const u16* __restrict__ Kg,
                                              const u16* __restrict__ Vg,
                                              const u16* __restrict__ Eg,
                                              u16* __restrict__ Og) {
    __shared__ u16 Qs[64 * 72];
    __shared__ u16 Ks[64 * 72];
    __shared__ u16 Vts[64 * 72];     // Vts[d][j] = V[c0+j][d]
    __shared__ u16 Ps[64 * 72];
    __shared__ float arena[64 * 128]; // QE f32 [64][128]; front 18KB doubles as Es u16 [128][72]
    u16* Es = (u16*)arena;

    const int i0 = blockIdx.x << 6;
    const int hd = blockIdx.y;
    const int b  = blockIdx.z;
    const int t  = threadIdx.x;
    const int lane = t & 63;
    const int n16 = lane & 15;
    const int quad = lane >> 4;
    const int w = t >> 6;
    const int rw = w << 4;

    const size_t gb = (size_t)b * SEQ * DM + hd * DH;

    // stage Q tile (64x64)
    {
        int c = t, r = c >> 3, k8 = (c & 7) << 3;
        *(uint4*)&Qs[r * 72 + k8] = *(const uint4*)(Qg + gb + (size_t)(i0 + r) * DM + k8);
        c = t + 256; r = c >> 3; k8 = (c & 7) << 3;
        *(uint4*)&Qs[r * 72 + k8] = *(const uint4*)(Qg + gb + (size_t)(i0 + r) * DM + k8);
    }

    const f32x4 z = {0.f, 0.f, 0.f, 0.f};
    f32x4 Oa[4] = {z, z, z, z};
    float m_run[4] = {-1e30f, -1e30f, -1e30f, -1e30f};
    float l_run[4] = {0.f, 0.f, 0.f, 0.f};

    for (int ct = 0; ct < 16; ++ct) {
        const int c0 = ct << 6;
        const bool active = (c0 <= i0);

        __syncthreads();   // protect prior-iter LDS consumers before restaging
        {   // stage K tile
            int c = t, r = c >> 3, k8 = (c & 7) << 3;
            *(uint4*)&Ks[r * 72 + k8] = *(const uint4*)(Kg + gb + (size_t)(c0 + r) * DM + k8);
            c = t + 256; r = c >> 3; k8 = (c & 7) << 3;
            *(uint4*)&Ks[r * 72 + k8] = *(const uint4*)(Kg + gb + (size_t)(c0 + r) * DM + k8);
        }
        {   // stage V tile transposed
            int c = t, j = c >> 3, d8 = (c & 7) << 3;
            uint4 v = *(const uint4*)(Vg + gb + (size_t)(c0 + j) * DM + d8);
            const u16* pv = (const u16*)&v;
#pragma unroll
            for (int e = 0; e < 8; ++e) Vts[(d8 + e) * 72 + j] = pv[e];
            c = t + 256; j = c >> 3; d8 = (c & 7) << 3;
            v = *(const uint4*)(Vg + gb + (size_t)(c0 + j) * DM + d8);
            const u16* pv2 = (const u16*)&v;
#pragma unroll
            for (int e = 0; e < 8; ++e) Vts[(d8 + e) * 72 + j] = pv2[e];
        }
        if (active) {      // stage E window: rows ebase..ebase+127 (clamped)
            const int eb = 960 - i0 + c0;
#pragma unroll
            for (int p = 0; p < 4; ++p) {
                const int c = t + (p << 8);
                const int u = c >> 3, k8 = (c & 7) << 3;
                int m = eb + u; m = m > 1023 ? 1023 : m;
                *(uint4*)&Es[u * 72 + k8] = *(const uint4*)(Eg + (size_t)m * DH + k8);
            }
        }
        __syncthreads();

        const s16x8 qa0 = *(const s16x8*)&Qs[(rw + n16) * 72 + quad * 8];
        const s16x8 qa1 = *(const s16x8*)&Qs[(rw + n16) * 72 + quad * 8 + 32];

        // S = Q K^T
        f32x4 S[4] = {z, z, z, z};
#pragma unroll
        for (int cb = 0; cb < 4; ++cb) {
            const s16x8 k0 = *(const s16x8*)&Ks[(cb * 16 + n16) * 72 + quad * 8];
            const s16x8 k1 = *(const s16x8*)&Ks[(cb * 16 + n16) * 72 + quad * 8 + 32];
            S[cb] = MFMA16(qa0, k0, S[cb]);
            S[cb] = MFMA16(qa1, k1, S[cb]);
        }

        if (active) {
            // QE = Q @ E_window^T  (64 x 128)
            f32x4 qe[8];
#pragma unroll
            for (int ub = 0; ub < 8; ++ub) qe[ub] = z;
#pragma unroll
            for (int ub = 0; ub < 8; ++ub) {
                const s16x8 e0 = *(const s16x8*)&Es[(ub * 16 + n16) * 72 + quad * 8];
                const s16x8 e1 = *(const s16x8*)&Es[(ub * 16 + n16) * 72 + quad * 8 + 32];
                qe[ub] = MFMA16(qa0, e0, qe[ub]);
                qe[ub] = MFMA16(qa1, e1, qe[ub]);
            }
            __syncthreads();   // all waves done reading Es before arena overwrite
#pragma unroll
            for (int ub = 0; ub < 8; ++ub)
#pragma unroll
                for (int rr = 0; rr < 4; ++rr)
                    arena[(rw + quad * 4 + rr) * 128 + ub * 16 + n16] = qe[ub][rr];
            const int dqc = i0 - c0;
#pragma unroll
            for (int cb = 0; cb < 4; ++cb)
#pragma unroll
                for (int rr = 0; rr < 4; ++rr) {
                    const int ir = rw + quad * 4 + rr;
                    const int d = cb * 16 + n16 - ir;           // ic - ir
                    const float srel = (d <= dqc) ? arena[ir * 128 + 63 + d] : 0.f;
                    S[cb][rr] = (S[cb][rr] + srel) * 0.125f;
                }
        } else {
#pragma unroll
            for (int cb = 0; cb < 4; ++cb)
#pragma unroll
                for (int rr = 0; rr < 4; ++rr) S[cb][rr] *= 0.125f;
        }

        // online softmax (row r = quad*4+rr lives across the quad's 16 lanes)
        float mt[4], al[4], rs[4], p[4][4];
#pragma unroll
        for (int rr = 0; rr < 4; ++rr)
            mt[rr] = fmaxf(fmaxf(S[0][rr], S[1][rr]), fmaxf(S[2][rr], S[3][rr]));
#pragma unroll
        for (int rr = 0; rr < 4; ++rr) {
            mt[rr] = fmaxf(mt[rr], __shfl_xor(mt[rr], 1, 64));
            mt[rr] = fmaxf(mt[rr], __shfl_xor(mt[rr], 2, 64));
            mt[rr] = fmaxf(mt[rr], __shfl_xor(mt[rr], 4, 64));
            mt[rr] = fmaxf(mt[rr], __shfl_xor(mt[rr], 8, 64));
        }
#pragma unroll
        for (int rr = 0; rr < 4; ++rr) {
            const float mn = fmaxf(m_run[rr], mt[rr]);
            al[rr] = __expf(m_run[rr] - mn);
            m_run[rr] = mn;
        }
#pragma unroll
        for (int cb = 0; cb < 4; ++cb)
#pragma unroll
            for (int rr = 0; rr < 4; ++rr) p[cb][rr] = __expf(S[cb][rr] - m_run[rr]);
#pragma unroll
        for (int rr = 0; rr < 4; ++rr) {
            rs[rr] = p[0][rr] + p[1][rr] + p[2][rr] + p[3][rr];
            rs[rr] += __shfl_xor(rs[rr], 1, 64);
            rs[rr] += __shfl_xor(rs[rr], 2, 64);
            rs[rr] += __shfl_xor(rs[rr], 4, 64);
            rs[rr] += __shfl_xor(rs[rr], 8, 64);
            l_run[rr] = l_run[rr] * al[rr] + rs[rr];
        }
#pragma unroll
        for (int db = 0; db < 4; ++db)
#pragma unroll
            for (int rr = 0; rr < 4; ++rr) Oa[db][rr] *= al[rr];
        // P -> LDS (A-operand layout for PV)
#pragma unroll
        for (int cb = 0; cb < 4; ++cb)
#pragma unroll
            for (int rr = 0; rr < 4; ++rr)
                Ps[(rw + quad * 4 + rr) * 72 + cb * 16 + n16] = f2b(p[cb][rr]);

        const s16x8 pa0 = *(const s16x8*)&Ps[(rw + n16) * 72 + quad * 8];
        const s16x8 pa1 = *(const s16x8*)&Ps[(rw + n16) * 72 + quad * 8 + 32];
#pragma unroll
        for (int db = 0; db < 4; ++db) {
            const s16x8 v0 = *(const s16x8*)&Vts[(db * 16 + n16) * 72 + quad * 8];
            const s16x8 v1 = *(const s16x8*)&Vts[(db * 16 + n16) * 72 + quad * 8 + 32];
            Oa[db] = MFMA16(pa0, v0, Oa[db]);
            Oa[db] = MFMA16(pa1, v1, Oa[db]);
        }
    }

    float inv[4];
#pragma unroll
    for (int rr = 0; rr < 4; ++rr) inv[rr] = 1.f / l_run[rr];
#pragma unroll
    for (int db = 0; db < 4; ++db)
#pragma unroll
        for (int rr = 0; rr < 4; ++rr) {
            const int row = i0 + rw + quad * 4 + rr;
            Og[gb + (size_t)row * DM + db * 16 + n16] = f2b(Oa[db][rr] * inv[rr]);
        }
}

// ---------------------------------------------------------------------------
// LayerNorm(A + R)*sc + bi -> Y (f32, may alias A) and Yb (bf16)
// ---------------------------------------------------------------------------
__global__ __launch_bounds__(128) void k_ln(const float* __restrict__ A,
                                            const float* __restrict__ R,
                                            const float* __restrict__ sc,
                                            const float* __restrict__ bi,
                                            float* __restrict__ Y,
                                            u16* __restrict__ Yb) {
    const int r = blockIdx.x, t = threadIdx.x;
    const float4 a = ((const float4*)(A + (size_t)r * DM))[t];
    const float4 b = ((const float4*)(R + (size_t)r * DM))[t];
    float4 v;
    v.x = a.x + b.x; v.y = a.y + b.y; v.z = a.z + b.z; v.w = a.w + b.w;

    float s = v.x + v.y + v.z + v.w;
#pragma unroll
    for (int o = 32; o > 0; o >>= 1) s += __shfl_down(s, o, 64);
    __shared__ float r1[2], r2[2];
    if ((t & 63) == 0) r1[t >> 6] = s;
    __syncthreads();
    const float mean = (r1[0] + r1[1]) * (1.f / 512.f);

    float4 d;
    d.x = v.x - mean; d.y = v.y - mean; d.z = v.z - mean; d.w = v.w - mean;
    float q = d.x * d.x + d.y * d.y + d.z * d.z + d.w * d.w;
#pragma unroll
    for (int o = 32; o > 0; o >>= 1) q += __shfl_down(q, o, 64);
    if ((t & 63) == 0) r2[t >> 6] = q;
    __syncthreads();
    const float rsq = rsqrtf((r2[0] + r2[1]) * (1.f / 512.f) + 1e-6f);

    const float4 s4 = ((const float4*)sc)[t];
    const float4 b4 = ((const float4*)bi)[t];
    float4 y;
    y.x = d.x * rsq * s4.x + b4.x;
    y.y = d.y * rsq * s4.y + b4.y;
    y.z = d.z * rsq * s4.z + b4.z;
    y.w = d.w * rsq * s4.w + b4.w;
    ((float4*)(Y + (size_t)r * DM))[t] = y;
    u16x4 yb = { f2b(y.x), f2b(y.y), f2b(y.z), f2b(y.w) };
    ((u16x4*)(Yb + (size_t)r * DM))[t] = yb;
}

// ---------------------------------------------------------------------------
// out[b,o] = tanh(h[b,0,:] @ Wf[:,o] + bf[o])
// ---------------------------------------------------------------------------
__global__ __launch_bounds__(512) void k_head(const float* __restrict__ h,
                                              const float* __restrict__ Wf,
                                              const float* __restrict__ bf,
                                              float* __restrict__ out) {
    const int t = threadIdx.x;
    const int w = t >> 6, lane = t & 63;
    const int b = w >> 1, oo = w & 1;
    float s = 0.f;
    for (int d = lane; d < DM; d += 64)
        s += h[(size_t)b * SEQ * DM + d] * Wf[d * NOUT + oo];
#pragma unroll
    for (int o = 32; o > 0; o >>= 1) s += __shfl_down(s, o, 64);
    if (lane == 0) out[b * NOUT + oo] = tanhf(s + bf[oo]);
}

// ---------------------------------------------------------------------------
extern "C" void kernel_launch(void* const* d_in, const int* in_sizes, int n_in,
                              void* d_out, int out_size, void* d_ws, size_t ws_size,
                              hipStream_t stream) {
    const int*   x    = (const int*)d_in[0];
    const float* emb  = (const float*)d_in[1];
    const float* pos  = (const float*)d_in[2];
    const float* Wq   = (const float*)d_in[3];
    const float* bq   = (const float*)d_in[4];
    const float* Wk   = (const float*)d_in[5];
    const float* bk   = (const float*)d_in[6];
    const float* Wv   = (const float*)d_in[7];
    const float* bv   = (const float*)d_in[8];
    const float* Wo   = (const float*)d_in[9];
    const float* bo   = (const float*)d_in[10];
    const float* E    = (const float*)d_in[11];
    const float* W1   = (const float*)d_in[12];
    const float* b1   = (const float*)d_in[13];
    const float* W2   = (const float*)d_in[14];
    const float* b2   = (const float*)d_in[15];
    const float* ln1s = (const float*)d_in[16];
    const float* ln1b = (const float*)d_in[17];
    const float* ln2s = (const float*)d_in[18];
    const float* ln2b = (const float*)d_in[19];
    const float* Wf   = (const float*)d_in[20];
    const float* bfp  = (const float*)d_in[21];
    float* out = (float*)d_out;

    // workspace map (46.125 MB total). NOTE: no trailing backslashes in
    // these comments (a '\' at end of a // comment swallows the next line).
    char* W = (char*)d_ws;
    float* h    = (float*)(W);                         // 8 MB f32 residual
    float* h1   = (float*)(W + (8u  << 20));           // 8 MB f32 (attn-proj out / post-LN1)
    u16*   hb   = (u16*)  (W + (16u << 20));           // 4 MB bf16 of h
    u16*   h1b  = (u16*)  (W + (20u << 20));           // 4 MB bf16 of h1
    u16*   qb   = (u16*)  (W + (24u << 20));           // 4 MB q  (midb aliases 24..40 MB)
    u16*   kb   = (u16*)  (W + (28u << 20));           // 4 MB k
    u16*   vb   = (u16*)  (W + (32u << 20));           // 4 MB v
    u16*   tb   = (u16*)  (W + (36u << 20));           // 4 MB attention out
    u16*   midb = qb;                                  // [4096][2048] FFN inner
    u16*   Wqkvt= (u16*)  (W + (40u << 20));           // 1.5 MB [1536][512]
    u16*   Wot  = (u16*)  (W + (40u << 20) + 1572864); // 0.5 MB [512][512]
    u16*   W1t  = (u16*)  (W + (42u << 20));           // 2 MB [2048][512]
    u16*   W2t  = (u16*)  (W + (44u << 20));           // 2 MB [512][2048]
    u16*   Ebf  = (u16*)  (W + (46u << 20));           // 128 KB [1024][64]

    const int M = BATCH * SEQ;                       // 4096
    const size_t SEG = (size_t)M * DM;               // 2,097,152 elems (q->k->v stride)

    k_embed<<<(BATCH * SEQ * DM / 4) / 256, 256, 0, stream>>>(x, emb, pos, h, hb);

    for (int l = 0; l < NL; ++l) {
        k_conv<<<3136, 256, 0, stream>>>(Wq, Wk, Wv, Wo, W1, W2, E,
                                         Wqkvt, Wot, W1t, W2t, Ebf, l);
        // QKV fused: N=1536 segmented into qb/kb/vb
        k_mm<0, 1><<<dim3(12, 32), 256, 0, stream>>>(hb, Wqkvt,
            bq + l * DM, bk + l * DM, bv + l * DM, nullptr, qb, 512, 512, 9, SEG);
        k_attn<<<dim3(16, 8, 4), 256, 0, stream>>>(qb, kb, vb, Ebf, tb);
        k_mm<0, 0><<<dim3(4, 32), 256, 0, stream>>>(tb, Wot,
            bo + l * DM, bo + l * DM, bo + l * DM, h1, nullptr, 512, 512, 30, 0);
        k_ln<<<M, 128, 0, stream>>>(h1, h, ln1s + l * DM, ln1b + l * DM, h1, h1b);
        k_mm<1, 1><<<dim3(16, 32), 256, 0, stream>>>(h1b, W1t,
            b1 + l * DI, b1 + l * DI, b1 + l * DI, nullptr, midb, 512, 2048, 30, 0);
        k_mm<0, 0><<<dim3(4, 32), 256, 0, stream>>>(midb, W2t,
            b2 + l * DM, b2 + l * DM, b2 + l * DM, h, nullptr, 2048, 512, 30, 0);
        k_ln<<<M, 128, 0, stream>>>(h, h1, ln2s + l * DM, ln2b + l * DM, h, hb);
    }

    k_head<<<1, 512, 0, stream>>>(h, Wf, bfp, out);
}